// Round 1
// baseline (834.181 us; speedup 1.0000x reference)
//
#include <hip/hip_runtime.h>
#include <cstdint>
#include <cstddef>

#define NN 100000
#define NE 1000000

// ---------------- CSR build ----------------

__global__ __launch_bounds__(256) void k_count(const int* __restrict__ dst, int* __restrict__ cnt){
  int e = blockIdx.x*256 + threadIdx.x;
  if (e < NE) atomicAdd(&cnt[dst[e]], 1);
}

__global__ __launch_bounds__(256) void k_scan_local(const int* __restrict__ cnt, int* __restrict__ rowptr,
                                                    int* __restrict__ bsum){
  __shared__ int sm[256];
  int t = threadIdx.x;
  int i = blockIdx.x*256 + t;
  int v = (i < NN) ? cnt[i] : 0;
  sm[t] = v;
  __syncthreads();
  for (int off=1; off<256; off<<=1){
    int u = (t>=off) ? sm[t-off] : 0;
    __syncthreads();
    sm[t] += u;
    __syncthreads();
  }
  if (i < NN) rowptr[i] = sm[t] - v;   // exclusive partial
  if (t == 255) bsum[blockIdx.x] = sm[255];
}

__global__ __launch_bounds__(512) void k_scan_bsum(const int* __restrict__ bsum, int* __restrict__ boff, int nb){
  __shared__ int sm[512];
  int t = threadIdx.x;
  int v = (t < nb) ? bsum[t] : 0;
  sm[t] = v;
  __syncthreads();
  for (int off=1; off<512; off<<=1){
    int u = (t>=off) ? sm[t-off] : 0;
    __syncthreads();
    sm[t] += u;
    __syncthreads();
  }
  if (t < nb) boff[t] = sm[t] - v;     // exclusive
}

__global__ __launch_bounds__(256) void k_scan_add(int* __restrict__ rowptr, const int* __restrict__ boff){
  int i = blockIdx.x*256 + threadIdx.x;
  if (i < NN) rowptr[i] += boff[i>>8];
  else if (i == NN) rowptr[NN] = NE;
}

__global__ __launch_bounds__(256) void k_fill(const int* __restrict__ src, const int* __restrict__ dst,
                                              const int* __restrict__ rowptr, int* __restrict__ cnt2,
                                              int* __restrict__ csr){
  int e = blockIdx.x*256 + threadIdx.x;
  if (e < NE){
    int d = dst[e];
    int p = atomicAdd(&cnt2[d], 1);
    csr[rowptr[d] + p] = src[e];
  }
}

// ---------------- GEMM: C[M,NC] = A[M,K] @ B[K,NC], fp32 ----------------

template<int NC>
__global__ __launch_bounds__(256) void k_gemm(const float* __restrict__ A, const float* __restrict__ B,
                                              float* __restrict__ C, int M, int K){
  constexpr int CN = NC/16;
  __shared__ float Bs[32][NC];
  __shared__ float As[64][33];
  int t = threadIdx.x;
  int tc = t & 15, tr = t >> 4;
  int row0 = blockIdx.x * 64;
  float acc[4][CN];
  #pragma unroll
  for (int i=0;i<4;i++)
    #pragma unroll
    for (int j=0;j<CN;j++) acc[i][j] = 0.f;

  for (int k0=0; k0<K; k0+=32){
    for (int idx=t; idx<32*NC; idx+=256){
      int kk = idx / NC, c = idx % NC;
      Bs[kk][c] = B[(size_t)(k0+kk)*NC + c];
    }
    for (int idx=t; idx<512; idx+=256){
      int r = idx >> 3, c4 = idx & 7;
      float4 v;
      if (row0 + r < M) v = *(const float4*)(A + (size_t)(row0+r)*K + k0 + c4*4);
      else v = make_float4(0.f,0.f,0.f,0.f);
      As[r][c4*4+0]=v.x; As[r][c4*4+1]=v.y; As[r][c4*4+2]=v.z; As[r][c4*4+3]=v.w;
    }
    __syncthreads();
    #pragma unroll
    for (int kk=0; kk<32; kk++){
      float a[4], b[CN];
      #pragma unroll
      for (int i=0;i<4;i++) a[i] = As[tr*4+i][kk];
      #pragma unroll
      for (int j=0;j<CN;j++) b[j] = Bs[kk][tc*CN+j];
      #pragma unroll
      for (int i=0;i<4;i++)
        #pragma unroll
        for (int j=0;j<CN;j++) acc[i][j] += a[i]*b[j];
    }
    __syncthreads();
  }
  #pragma unroll
  for (int i=0;i<4;i++){
    int row = row0 + tr*4 + i;
    if (row < M){
      #pragma unroll
      for (int j=0;j<CN;j++) C[(size_t)row*NC + tc*CN + j] = acc[i][j];
    }
  }
}

// ---------------- el/er: attention logits per (node, head) ----------------

template<int H>
__global__ __launch_bounds__(256) void k_elr(const float* __restrict__ feat, const float* __restrict__ al,
                                             const float* __restrict__ ar, float* __restrict__ el,
                                             float* __restrict__ er){
  int i = blockIdx.x*256 + threadIdx.x;   // i = n*H + h
  if (i >= NN*H) return;
  int h = i % H;
  const float* f = feat + (size_t)i*32;
  const float* a = al + h*32;
  const float* b = ar + h*32;
  float sl = 0.f, sr = 0.f;
  #pragma unroll
  for (int d=0; d<32; d++){
    float v = f[d];
    sl += v * a[d];
    sr += v * b[d];
  }
  el[i] = sl; er[i] = sr;
}

// ---------------- aggregation: one wave per dst node ----------------
// edge softmax (max, sum via shfl_xor groups per head) + gather-accumulate.

template<int H>
__global__ __launch_bounds__(256) void k_agg(const int* __restrict__ rowptr, const int* __restrict__ csr,
                                             const float* __restrict__ feat,
                                             const float* __restrict__ el, const float* __restrict__ er,
                                             const float* __restrict__ res, const float* __restrict__ bias,
                                             float* __restrict__ out, int act){
  constexpr int F = H*32;
  int lane = threadIdx.x & 63;
  int node = blockIdx.x*4 + (threadIdx.x >> 6);   // NN % 4 == 0

  int beg = rowptr[node], end = rowptr[node+1];
  int deg = end - beg;

  int hA = lane & (H-1);
  float erA = er[(size_t)node*H + hA];
  float m = -INFINITY;
  for (int idx = lane; idx < deg*H; idx += 64){
    int s = csr[beg + ((H==4) ? (idx>>2) : idx)];
    float e = el[(size_t)s*H + hA] + erA;
    e = (e > 0.f) ? e : 0.2f*e;
    m = fmaxf(m, e);
  }
  #pragma unroll
  for (int off=H; off<64; off<<=1) m = fmaxf(m, __shfl_xor(m, off));

  float ss = 0.f;
  for (int idx = lane; idx < deg*H; idx += 64){
    int s = csr[beg + ((H==4) ? (idx>>2) : idx)];
    float e = el[(size_t)s*H + hA] + erA;
    e = (e > 0.f) ? e : 0.2f*e;
    ss += __expf(e - m);
  }
  #pragma unroll
  for (int off=H; off<64; off<<=1) ss += __shfl_xor(ss, off);

  float acc0 = 0.f, acc1 = 0.f;
  int h0 = (H==4) ? (lane>>5) : 0;
  float m0 = __shfl(m, h0);
  float s0 = __shfl(ss, h0);
  float er0 = er[(size_t)node*H + h0];
  float m1 = 0.f, s1 = 1.f, er1 = 0.f;
  if (H == 4){
    m1 = __shfl(m, h0+2);
    s1 = __shfl(ss, h0+2);
    er1 = er[(size_t)node*4 + h0+2];
  }
  float inv0 = (deg > 0) ? 1.f/s0 : 0.f;
  float inv1 = (deg > 0) ? 1.f/s1 : 0.f;

  for (int ei=0; ei<deg; ei++){
    int s = csr[beg + ei];
    const float* fr = feat + (size_t)s*F;
    float e0 = el[(size_t)s*H + h0] + er0;
    e0 = (e0>0.f) ? e0 : 0.2f*e0;
    float a0 = __expf(e0 - m0) * inv0;
    if (H == 4){
      float e1 = el[(size_t)s*4 + h0+2] + er1;
      e1 = (e1>0.f) ? e1 : 0.2f*e1;
      float a1 = __expf(e1 - m1) * inv1;
      acc0 += a0 * fr[lane];
      acc1 += a1 * fr[lane+64];
    } else {
      if (lane < 32) acc0 += a0 * fr[lane];
    }
  }

  if (H == 4){
    float o0 = acc0, o1 = acc1;
    if (res){ o0 += res[(size_t)node*F + lane]; o1 += res[(size_t)node*F + lane + 64]; }
    o0 += bias[lane]; o1 += bias[lane+64];
    if (act){
      o0 = (o0>0.f) ? o0 : __expf(o0)-1.f;
      o1 = (o1>0.f) ? o1 : __expf(o1)-1.f;
    }
    out[(size_t)node*F + lane]      = o0;
    out[(size_t)node*F + lane + 64] = o1;
  } else {
    if (lane < 32){
      float o0 = acc0;
      if (res) o0 += res[(size_t)node*32 + lane];
      o0 += bias[lane];
      if (act) o0 = (o0>0.f) ? o0 : __expf(o0)-1.f;
      out[(size_t)node*32 + lane] = o0;
    }
  }
}

// ---------------- final FC: out[N,40] = h[N,32] @ Wfc[32,40] + bfc ----------------

__global__ __launch_bounds__(256) void k_fc(const float* __restrict__ h, const float* __restrict__ W,
                                            const float* __restrict__ b, float* __restrict__ out){
  __shared__ float Ws[32*40];
  __shared__ float Hs[64][33];
  __shared__ float bs[40];
  int t = threadIdx.x;
  for (int i=t; i<1280; i+=256) Ws[i] = W[i];
  if (t < 40) bs[t] = b[t];
  int n0 = blockIdx.x*64;
  for (int idx=t; idx<512; idx+=256){
    int r = idx>>3, c4 = idx&7;
    float4 v;
    if (n0 + r < NN) v = *(const float4*)(h + (size_t)(n0+r)*32 + c4*4);
    else v = make_float4(0.f,0.f,0.f,0.f);
    Hs[r][c4*4+0]=v.x; Hs[r][c4*4+1]=v.y; Hs[r][c4*4+2]=v.z; Hs[r][c4*4+3]=v.w;
  }
  __syncthreads();
  int n = t>>2, cg = t&3;
  float acc[10];
  #pragma unroll
  for (int j=0;j<10;j++) acc[j] = 0.f;
  #pragma unroll
  for (int k=0;k<32;k++){
    float hv = Hs[n][k];
    #pragma unroll
    for (int j=0;j<10;j++) acc[j] += hv * Ws[k*40 + cg + 4*j];
  }
  int row = n0 + n;
  if (row < NN){
    #pragma unroll
    for (int j=0;j<10;j++) out[(size_t)row*40 + cg + 4*j] = acc[j] + bs[cg+4*j];
  }
}

// ---------------- launch ----------------

extern "C" void kernel_launch(void* const* d_in, const int* in_sizes, int n_in,
                              void* d_out, int out_size, void* d_ws, size_t ws_size,
                              hipStream_t stream){
  const float* x    = (const float*)d_in[0];
  const int*   src  = (const int*)  d_in[1];
  const int*   dst  = (const int*)  d_in[2];
  const float* W1   = (const float*)d_in[3];
  const float* al1  = (const float*)d_in[4];
  const float* ar1  = (const float*)d_in[5];
  const float* b1   = (const float*)d_in[6];
  const float* W2   = (const float*)d_in[7];
  const float* al2  = (const float*)d_in[8];
  const float* ar2  = (const float*)d_in[9];
  const float* b2   = (const float*)d_in[10];
  const float* W3   = (const float*)d_in[11];
  const float* al3  = (const float*)d_in[12];
  const float* ar3  = (const float*)d_in[13];
  const float* b3   = (const float*)d_in[14];
  const float* res3 = (const float*)d_in[15];
  const float* Wfc  = (const float*)d_in[16];
  const float* bfc  = (const float*)d_in[17];
  float* out = (float*)d_out;

  char* ws = (char*)d_ws;
  size_t o = 0;
  auto alloc = [&](size_t bytes)->char*{
    char* p = ws + o;
    o += (bytes + 255) & ~(size_t)255;
    return p;
  };
  int*   rowptr = (int*)  alloc((size_t)(NN+1)*4);
  int*   cnt    = (int*)  alloc((size_t)NN*4);
  int*   cnt2   = (int*)  alloc((size_t)NN*4);
  int*   bsum   = (int*)  alloc(512*4);
  int*   boff   = (int*)  alloc(512*4);
  int*   csr    = (int*)  alloc((size_t)NE*4);
  float* el     = (float*)alloc((size_t)NN*4*4);
  float* er     = (float*)alloc((size_t)NN*4*4);
  float* bufF   = (float*)alloc((size_t)NN*128*4);
  float* bufH1  = (float*)alloc((size_t)NN*128*4);
  float* bufH2  = (float*)alloc((size_t)NN*128*4);
  (void)ws_size; (void)n_in; (void)in_sizes; (void)out_size;

  // CSR build (graph identical across layers)
  hipMemsetAsync(cnt,  0, (size_t)NN*4, stream);
  hipMemsetAsync(cnt2, 0, (size_t)NN*4, stream);
  k_count<<<(NE+255)/256, 256, 0, stream>>>(dst, cnt);
  int nb = (NN+255)/256;  // 391
  k_scan_local<<<nb, 256, 0, stream>>>(cnt, rowptr, bsum);
  k_scan_bsum<<<1, 512, 0, stream>>>(bsum, boff, nb);
  k_scan_add<<<(NN+1+255)/256, 256, 0, stream>>>(rowptr, boff);
  k_fill<<<(NE+255)/256, 256, 0, stream>>>(src, dst, rowptr, cnt2, csr);

  int gemm_blocks = (NN+63)/64;

  // ---- Layer 1: 128 -> 4x32, no residual, ELU ----
  k_gemm<128><<<gemm_blocks, 256, 0, stream>>>(x, W1, bufF, NN, 128);
  k_elr<4><<<(NN*4+255)/256, 256, 0, stream>>>(bufF, al1, ar1, el, er);
  k_agg<4><<<NN/4, 256, 0, stream>>>(rowptr, csr, bufF, el, er, nullptr, b1, bufH1, 1);

  // ---- Layer 2: 128 -> 4x32, identity residual, ELU ----
  k_gemm<128><<<gemm_blocks, 256, 0, stream>>>(bufH1, W2, bufF, NN, 128);
  k_elr<4><<<(NN*4+255)/256, 256, 0, stream>>>(bufF, al2, ar2, el, er);
  k_agg<4><<<NN/4, 256, 0, stream>>>(rowptr, csr, bufF, el, er, bufH1, b2, bufH2, 1);

  // ---- Layer 3: 128 -> 1x32, projected residual, no act ----
  k_gemm<32><<<gemm_blocks, 256, 0, stream>>>(bufH2, W3, bufF, NN, 128);      // feat3 [N,32]
  float* res3p = bufH1;                                                        // h1 dead now
  k_gemm<32><<<gemm_blocks, 256, 0, stream>>>(bufH2, res3, res3p, NN, 128);   // h2 @ res3
  k_elr<1><<<(NN+255)/256, 256, 0, stream>>>(bufF, al3, ar3, el, er);
  float* h3 = bufH2;                                                           // h2 dead after GEMMs
  k_agg<1><<<NN/4, 256, 0, stream>>>(rowptr, csr, bufF, el, er, res3p, b3, h3, 0);

  // ---- classifier ----
  k_fc<<<gemm_blocks, 256, 0, stream>>>(h3, Wfc, bfc, out);
}

// Round 2
// 599.476 us; speedup vs baseline: 1.3915x; 1.3915x over previous
//
#include <hip/hip_runtime.h>
#include <cstdint>
#include <cstddef>

#define NN 100000
#define NE 1000000

typedef unsigned int uint;
typedef unsigned short ushort;

__device__ __forceinline__ ushort f2bf(float f){
  uint u = __float_as_uint(f);
  u += 0x7fffu + ((u >> 16) & 1u);     // round-to-nearest-even
  return (ushort)(u >> 16);
}
__device__ __forceinline__ float bflo(uint p){ return __uint_as_float(p << 16); }
__device__ __forceinline__ float bfhi(uint p){ return __uint_as_float(p & 0xffff0000u); }

// ---------------- CSR build ----------------

__global__ __launch_bounds__(256) void k_count(const int* __restrict__ dst, int* __restrict__ cnt){
  int e = blockIdx.x*256 + threadIdx.x;
  if (e < NE) atomicAdd(&cnt[dst[e]], 1);
}

__global__ __launch_bounds__(256) void k_scan_local(const int* __restrict__ cnt, int* __restrict__ rowptr,
                                                    int* __restrict__ bsum){
  __shared__ int sm[256];
  int t = threadIdx.x;
  int i = blockIdx.x*256 + t;
  int v = (i < NN) ? cnt[i] : 0;
  sm[t] = v;
  __syncthreads();
  for (int off=1; off<256; off<<=1){
    int u = (t>=off) ? sm[t-off] : 0;
    __syncthreads();
    sm[t] += u;
    __syncthreads();
  }
  if (i < NN) rowptr[i] = sm[t] - v;
  if (t == 255) bsum[blockIdx.x] = sm[255];
}

__global__ __launch_bounds__(512) void k_scan_bsum(const int* __restrict__ bsum, int* __restrict__ boff, int nb){
  __shared__ int sm[512];
  int t = threadIdx.x;
  int v = (t < nb) ? bsum[t] : 0;
  sm[t] = v;
  __syncthreads();
  for (int off=1; off<512; off<<=1){
    int u = (t>=off) ? sm[t-off] : 0;
    __syncthreads();
    sm[t] += u;
    __syncthreads();
  }
  if (t < nb) boff[t] = sm[t] - v;
}

__global__ __launch_bounds__(256) void k_scan_add(int* __restrict__ rowptr, const int* __restrict__ boff){
  int i = blockIdx.x*256 + threadIdx.x;
  if (i < NN) rowptr[i] += boff[i>>8];
  else if (i == NN) rowptr[NN] = NE;
}

__global__ __launch_bounds__(256) void k_fill(const int* __restrict__ src, const int* __restrict__ dst,
                                              const int* __restrict__ rowptr, int* __restrict__ cnt2,
                                              int* __restrict__ csr){
  int e = blockIdx.x*256 + threadIdx.x;
  if (e < NE){
    int d = dst[e];
    int p = atomicAdd(&cnt2[d], 1);
    csr[rowptr[d] + p] = src[e];
  }
}

// ---------------- GEMM with fused el/er + bf16 feat epilogue ----------------
// FEAT=true : writes Cb (bf16 [M,NC]) and el/er ([M,NC/32]) from exact fp32 acc.
// FEAT=false: writes C (fp32 [M,NC]).

template<int NC, bool FEAT>
__global__ __launch_bounds__(256) void k_gemm(const float* __restrict__ A, const float* __restrict__ B,
                                              float* __restrict__ C, ushort* __restrict__ Cb,
                                              const float* __restrict__ al, const float* __restrict__ ar,
                                              float* __restrict__ el, float* __restrict__ er,
                                              int M, int K){
  constexpr int CN = NC/16;
  constexpr int H  = NC/32;
  __shared__ float Bs[32][NC];
  __shared__ float As[64][33];
  int t = threadIdx.x;
  int tc = t & 15, tr = t >> 4;
  int row0 = blockIdx.x * 64;
  float acc[4][CN];
  #pragma unroll
  for (int i=0;i<4;i++)
    #pragma unroll
    for (int j=0;j<CN;j++) acc[i][j] = 0.f;

  for (int k0=0; k0<K; k0+=32){
    for (int idx=t; idx<32*NC; idx+=256){
      int kk = idx / NC, c = idx % NC;
      Bs[kk][c] = B[(size_t)(k0+kk)*NC + c];
    }
    for (int idx=t; idx<512; idx+=256){
      int r = idx >> 3, c4 = idx & 7;
      float4 v;
      if (row0 + r < M) v = *(const float4*)(A + (size_t)(row0+r)*K + k0 + c4*4);
      else v = make_float4(0.f,0.f,0.f,0.f);
      As[r][c4*4+0]=v.x; As[r][c4*4+1]=v.y; As[r][c4*4+2]=v.z; As[r][c4*4+3]=v.w;
    }
    __syncthreads();
    #pragma unroll
    for (int kk=0; kk<32; kk++){
      float a[4], b[CN];
      #pragma unroll
      for (int i=0;i<4;i++) a[i] = As[tr*4+i][kk];
      #pragma unroll
      for (int j=0;j<CN;j++) b[j] = Bs[kk][tc*CN+j];
      #pragma unroll
      for (int i=0;i<4;i++)
        #pragma unroll
        for (int j=0;j<CN;j++) acc[i][j] += a[i]*b[j];
    }
    __syncthreads();
  }

  if (FEAT){
    // head / in-head column base for this thread's CN columns
    int h  = (NC==128) ? (tc >> 2) : 0;
    int cb = (NC==128) ? ((tc & 3) * CN) : (tc * CN);
    float alv[CN], arv[CN];
    #pragma unroll
    for (int j=0;j<CN;j++){ alv[j] = al[h*32+cb+j]; arv[j] = ar[h*32+cb+j]; }
    #pragma unroll
    for (int i=0;i<4;i++){
      int row = row0 + tr*4 + i;
      float pl = 0.f, pr = 0.f;
      #pragma unroll
      for (int j=0;j<CN;j++){ pl += acc[i][j]*alv[j]; pr += acc[i][j]*arv[j]; }
      if (NC==128){
        pl += __shfl_xor(pl,1); pl += __shfl_xor(pl,2);
        pr += __shfl_xor(pr,1); pr += __shfl_xor(pr,2);
      } else {
        #pragma unroll
        for (int off=1; off<16; off<<=1){ pl += __shfl_xor(pl,off); pr += __shfl_xor(pr,off); }
      }
      if (row < M){
        if (NC==128){
          uint4 pk;
          pk.x = (uint)f2bf(acc[i][0]) | ((uint)f2bf(acc[i][1])<<16);
          pk.y = (uint)f2bf(acc[i][2]) | ((uint)f2bf(acc[i][3])<<16);
          pk.z = (uint)f2bf(acc[i][4]) | ((uint)f2bf(acc[i][5])<<16);
          pk.w = (uint)f2bf(acc[i][6]) | ((uint)f2bf(acc[i][7])<<16);
          *(uint4*)(Cb + (size_t)row*NC + tc*CN) = pk;
          if ((tc & 3) == 0){ el[(size_t)row*H + h] = pl; er[(size_t)row*H + h] = pr; }
        } else {
          uint pk = (uint)f2bf(acc[i][0]) | ((uint)f2bf(acc[i][1])<<16);
          *(uint*)(Cb + (size_t)row*NC + tc*CN) = pk;
          if (tc == 0){ el[row] = pl; er[row] = pr; }
        }
      }
    }
  } else {
    #pragma unroll
    for (int i=0;i<4;i++){
      int row = row0 + tr*4 + i;
      if (row < M){
        #pragma unroll
        for (int j=0;j<CN;j++) C[(size_t)row*NC + tc*CN + j] = acc[i][j];
      }
    }
  }
}

// ---------------- aggregation: one wave per dst node, bf16 feat ----------------

template<int H>
__global__ __launch_bounds__(256) void k_agg(const int* __restrict__ rowptr, const int* __restrict__ csr,
                                             const ushort* __restrict__ feat,
                                             const float* __restrict__ el, const float* __restrict__ er,
                                             const float* __restrict__ res, const float* __restrict__ bias,
                                             float* __restrict__ out, int act){
  constexpr int F = H*32;
  int lane = threadIdx.x & 63;
  int node = blockIdx.x*4 + (threadIdx.x >> 6);

  int beg = rowptr[node], end = rowptr[node+1];
  int deg = end - beg;
  int tot = deg*H;

  // ---- pass 1: max (cache first stripe value in e0) ----
  int hA = lane & (H-1);
  float erA = er[(size_t)node*H + hA];
  float m = -INFINITY;
  float e0 = 0.f;
  if (lane < tot){
    int s = csr[beg + ((H==4) ? (lane>>2) : lane)];
    float e = el[(size_t)s*H + hA] + erA;
    e0 = (e > 0.f) ? e : 0.2f*e;
    m = e0;
  }
  for (int idx = lane+64; idx < tot; idx += 64){
    int s = csr[beg + ((H==4) ? (idx>>2) : idx)];
    float e = el[(size_t)s*H + hA] + erA;
    e = (e > 0.f) ? e : 0.2f*e;
    m = fmaxf(m, e);
  }
  #pragma unroll
  for (int off=H; off<64; off<<=1) m = fmaxf(m, __shfl_xor(m, off));

  // ---- pass 2: sum (reuse e0 for first stripe) ----
  float ss = 0.f;
  if (lane < tot) ss = __expf(e0 - m);
  for (int idx = lane+64; idx < tot; idx += 64){
    int s = csr[beg + ((H==4) ? (idx>>2) : idx)];
    float e = el[(size_t)s*H + hA] + erA;
    e = (e > 0.f) ? e : 0.2f*e;
    ss += __expf(e - m);
  }
  #pragma unroll
  for (int off=H; off<64; off<<=1) ss += __shfl_xor(ss, off);

  // ---- pass 3: gather-accumulate ----
  if (H == 4){
    int g = lane >> 4;                       // head owning features 2*lane,2*lane+1
    float mg  = __shfl(m, g);                // lane g (g<4) holds stats of head g
    float sg  = __shfl(ss, g);
    float erg = er[(size_t)node*4 + g];
    float inv = (deg > 0) ? 1.f/sg : 0.f;
    float a0 = 0.f, a1 = 0.f;

    int ei = 0;
    for (; ei+2 <= deg; ei += 2){
      int s0 = csr[beg+ei], s1 = csr[beg+ei+1];
      uint p0 = *(const uint*)(feat + (size_t)s0*128 + 2*lane);
      uint p1 = *(const uint*)(feat + (size_t)s1*128 + 2*lane);
      float eA = el[(size_t)s0*4 + g] + erg;
      float eB = el[(size_t)s1*4 + g] + erg;
      eA = (eA>0.f)?eA:0.2f*eA;  eB = (eB>0.f)?eB:0.2f*eB;
      float wA = __expf(eA - mg) * inv;
      float wB = __expf(eB - mg) * inv;
      a0 += wA*bflo(p0) + wB*bflo(p1);
      a1 += wA*bfhi(p0) + wB*bfhi(p1);
    }
    if (ei < deg){
      int s0 = csr[beg+ei];
      uint p0 = *(const uint*)(feat + (size_t)s0*128 + 2*lane);
      float eA = el[(size_t)s0*4 + g] + erg;
      eA = (eA>0.f)?eA:0.2f*eA;
      float wA = __expf(eA - mg) * inv;
      a0 += wA*bflo(p0);
      a1 += wA*bfhi(p0);
    }

    float o0 = a0, o1 = a1;
    if (res){
      float2 rv = *(const float2*)(res + (size_t)node*128 + 2*lane);
      o0 += rv.x; o1 += rv.y;
    }
    o0 += bias[2*lane]; o1 += bias[2*lane+1];
    if (act){
      o0 = (o0>0.f) ? o0 : __expf(o0)-1.f;
      o1 = (o1>0.f) ? o1 : __expf(o1)-1.f;
    }
    float2 ov; ov.x = o0; ov.y = o1;
    *(float2*)(out + (size_t)node*128 + 2*lane) = ov;
  } else {
    // H==1: 4 edges/iter across lane quads, lanes 0..15 own feature pairs
    float m0 = __shfl(m, 0);
    float s0v = __shfl(ss, 0);
    float er0 = er[node];
    float inv = (deg > 0) ? 1.f/s0v : 0.f;
    int sub = lane >> 4;       // 0..3 : edge sub-stream
    int fl  = lane & 15;       // feature pair 2*fl, 2*fl+1
    float a0 = 0.f, a1 = 0.f;
    for (int ei = sub; ei < deg; ei += 4){
      int s = csr[beg+ei];
      uint pv = *(const uint*)(feat + (size_t)s*32 + 2*fl);
      float e = el[s] + er0;
      e = (e>0.f)?e:0.2f*e;
      float w = __expf(e - m0) * inv;
      a0 += w*bflo(pv);
      a1 += w*bfhi(pv);
    }
    a0 += __shfl_xor(a0,16); a0 += __shfl_xor(a0,32);
    a1 += __shfl_xor(a1,16); a1 += __shfl_xor(a1,32);
    if (lane < 16){
      float o0 = a0, o1 = a1;
      if (res){
        float2 rv = *(const float2*)(res + (size_t)node*32 + 2*fl);
        o0 += rv.x; o1 += rv.y;
      }
      o0 += bias[2*fl]; o1 += bias[2*fl+1];
      if (act){
        o0 = (o0>0.f) ? o0 : __expf(o0)-1.f;
        o1 = (o1>0.f) ? o1 : __expf(o1)-1.f;
      }
      float2 ov; ov.x = o0; ov.y = o1;
      *(float2*)(out + (size_t)node*32 + 2*fl) = ov;
    }
  }
}

// ---------------- final FC: out[N,40] = h[N,32] @ Wfc[32,40] + bfc ----------------

__global__ __launch_bounds__(256) void k_fc(const float* __restrict__ h, const float* __restrict__ W,
                                            const float* __restrict__ b, float* __restrict__ out){
  __shared__ float Ws[32*40];
  __shared__ float Hs[64][33];
  __shared__ float bs[40];
  int t = threadIdx.x;
  for (int i=t; i<1280; i+=256) Ws[i] = W[i];
  if (t < 40) bs[t] = b[t];
  int n0 = blockIdx.x*64;
  for (int idx=t; idx<512; idx+=256){
    int r = idx>>3, c4 = idx&7;
    float4 v;
    if (n0 + r < NN) v = *(const float4*)(h + (size_t)(n0+r)*32 + c4*4);
    else v = make_float4(0.f,0.f,0.f,0.f);
    Hs[r][c4*4+0]=v.x; Hs[r][c4*4+1]=v.y; Hs[r][c4*4+2]=v.z; Hs[r][c4*4+3]=v.w;
  }
  __syncthreads();
  int n = t>>2, cg = t&3;
  float acc[10];
  #pragma unroll
  for (int j=0;j<10;j++) acc[j] = 0.f;
  #pragma unroll
  for (int k=0;k<32;k++){
    float hv = Hs[n][k];
    #pragma unroll
    for (int j=0;j<10;j++) acc[j] += hv * Ws[k*40 + cg + 4*j];
  }
  int row = n0 + n;
  if (row < NN){
    #pragma unroll
    for (int j=0;j<10;j++) out[(size_t)row*40 + cg + 4*j] = acc[j] + bs[cg+4*j];
  }
}

// ---------------- launch ----------------

extern "C" void kernel_launch(void* const* d_in, const int* in_sizes, int n_in,
                              void* d_out, int out_size, void* d_ws, size_t ws_size,
                              hipStream_t stream){
  const float* x    = (const float*)d_in[0];
  const int*   src  = (const int*)  d_in[1];
  const int*   dst  = (const int*)  d_in[2];
  const float* W1   = (const float*)d_in[3];
  const float* al1  = (const float*)d_in[4];
  const float* ar1  = (const float*)d_in[5];
  const float* b1   = (const float*)d_in[6];
  const float* W2   = (const float*)d_in[7];
  const float* al2  = (const float*)d_in[8];
  const float* ar2  = (const float*)d_in[9];
  const float* b2   = (const float*)d_in[10];
  const float* W3   = (const float*)d_in[11];
  const float* al3  = (const float*)d_in[12];
  const float* ar3  = (const float*)d_in[13];
  const float* b3   = (const float*)d_in[14];
  const float* res3 = (const float*)d_in[15];
  const float* Wfc  = (const float*)d_in[16];
  const float* bfc  = (const float*)d_in[17];
  float* out = (float*)d_out;

  char* ws = (char*)d_ws;
  size_t o = 0;
  auto alloc = [&](size_t bytes)->char*{
    char* p = ws + o;
    o += (bytes + 255) & ~(size_t)255;
    return p;
  };
  int*    rowptr = (int*)   alloc((size_t)(NN+1)*4);
  int*    cnt    = (int*)   alloc((size_t)NN*4);
  int*    cnt2   = (int*)   alloc((size_t)NN*4);
  int*    bsum   = (int*)   alloc(512*4);
  int*    boff   = (int*)   alloc(512*4);
  int*    csr    = (int*)   alloc((size_t)NE*4);
  float*  el     = (float*) alloc((size_t)NN*4*4);
  float*  er     = (float*) alloc((size_t)NN*4*4);
  ushort* featb  = (ushort*)alloc((size_t)NN*128*2);   // bf16 feat (25.6 MB, L2-resident)
  float*  bufH1  = (float*) alloc((size_t)NN*128*4);
  float*  bufH2  = (float*) alloc((size_t)NN*128*4);
  (void)ws_size; (void)n_in; (void)in_sizes; (void)out_size;

  // CSR build (graph identical across layers)
  hipMemsetAsync(cnt,  0, (size_t)NN*4, stream);
  hipMemsetAsync(cnt2, 0, (size_t)NN*4, stream);
  k_count<<<(NE+255)/256, 256, 0, stream>>>(dst, cnt);
  int nb = (NN+255)/256;
  k_scan_local<<<nb, 256, 0, stream>>>(cnt, rowptr, bsum);
  k_scan_bsum<<<1, 512, 0, stream>>>(bsum, boff, nb);
  k_scan_add<<<(NN+1+255)/256, 256, 0, stream>>>(rowptr, boff);
  k_fill<<<(NE+255)/256, 256, 0, stream>>>(src, dst, rowptr, cnt2, csr);

  int gemm_blocks = (NN+63)/64;

  // ---- Layer 1: 128 -> 4x32, no residual, ELU ----
  k_gemm<128,true><<<gemm_blocks, 256, 0, stream>>>(x, W1, nullptr, featb, al1, ar1, el, er, NN, 128);
  k_agg<4><<<NN/4, 256, 0, stream>>>(rowptr, csr, featb, el, er, nullptr, b1, bufH1, 1);

  // ---- Layer 2: 128 -> 4x32, identity residual, ELU ----
  k_gemm<128,true><<<gemm_blocks, 256, 0, stream>>>(bufH1, W2, nullptr, featb, al2, ar2, el, er, NN, 128);
  k_agg<4><<<NN/4, 256, 0, stream>>>(rowptr, csr, featb, el, er, bufH1, b2, bufH2, 1);

  // ---- Layer 3: 128 -> 1x32, projected residual, no act ----
  k_gemm<32,true><<<gemm_blocks, 256, 0, stream>>>(bufH2, W3, nullptr, featb, al3, ar3, el, er, NN, 128);
  float* res3p = bufH1;                                  // h1 dead now
  k_gemm<32,false><<<gemm_blocks, 256, 0, stream>>>(bufH2, res3, res3p, nullptr, nullptr, nullptr, nullptr, nullptr, NN, 128);
  float* h3 = bufH2;                                     // h2 dead after GEMMs
  k_agg<1><<<NN/4, 256, 0, stream>>>(rowptr, csr, featb, el, er, res3p, b3, h3, 0);

  // ---- classifier ----
  k_fc<<<gemm_blocks, 256, 0, stream>>>(h3, Wfc, bfc, out);
}

// Round 3
// 449.418 us; speedup vs baseline: 1.8561x; 1.3339x over previous
//
#include <hip/hip_runtime.h>
#include <cstdint>
#include <cstddef>

#define NN 100000
#define NE 1000000

typedef unsigned int uint;
typedef unsigned short ushort;
typedef __attribute__((ext_vector_type(8))) short bfrag;   // 8 bf16 = 4 VGPR
typedef __attribute__((ext_vector_type(4))) float f32x4;

__device__ __forceinline__ ushort f2bf(float f){
  uint u = __float_as_uint(f);
  u += 0x7fffu + ((u >> 16) & 1u);     // round-to-nearest-even
  return (ushort)(u >> 16);
}
__device__ __forceinline__ float bflo(uint p){ return __uint_as_float(p << 16); }
__device__ __forceinline__ float bfhi(uint p){ return __uint_as_float(p & 0xffff0000u); }

// ---------------- CSR build ----------------

__global__ __launch_bounds__(256) void k_count(const int* __restrict__ dst, int* __restrict__ cnt){
  int e = blockIdx.x*256 + threadIdx.x;
  if (e < NE) atomicAdd(&cnt[dst[e]], 1);
}

__global__ __launch_bounds__(256) void k_scan_local(const int* __restrict__ cnt, int* __restrict__ rowptr,
                                                    int* __restrict__ bsum){
  __shared__ int sm[256];
  int t = threadIdx.x;
  int i = blockIdx.x*256 + t;
  int v = (i < NN) ? cnt[i] : 0;
  sm[t] = v;
  __syncthreads();
  for (int off=1; off<256; off<<=1){
    int u = (t>=off) ? sm[t-off] : 0;
    __syncthreads();
    sm[t] += u;
    __syncthreads();
  }
  if (i < NN) rowptr[i] = sm[t] - v;
  if (t == 255) bsum[blockIdx.x] = sm[255];
}

__global__ __launch_bounds__(512) void k_scan_bsum(const int* __restrict__ bsum, int* __restrict__ boff, int nb){
  __shared__ int sm[512];
  int t = threadIdx.x;
  int v = (t < nb) ? bsum[t] : 0;
  sm[t] = v;
  __syncthreads();
  for (int off=1; off<512; off<<=1){
    int u = (t>=off) ? sm[t-off] : 0;
    __syncthreads();
    sm[t] += u;
    __syncthreads();
  }
  if (t < nb) boff[t] = sm[t] - v;
}

__global__ __launch_bounds__(256) void k_scan_add(int* __restrict__ rowptr, const int* __restrict__ boff){
  int i = blockIdx.x*256 + threadIdx.x;
  if (i < NN) rowptr[i] += boff[i>>8];
  else if (i == NN) rowptr[NN] = NE;
}

__global__ __launch_bounds__(256) void k_fill(const int* __restrict__ src, const int* __restrict__ dst,
                                              const int* __restrict__ rowptr, int* __restrict__ cnt2,
                                              int* __restrict__ csr){
  int e = blockIdx.x*256 + threadIdx.x;
  if (e < NE){
    int d = dst[e];
    int p = atomicAdd(&cnt2[d], 1);
    csr[rowptr[d] + p] = src[e];
  }
}

// ---------------- fp32 -> bf16 cast (x) ----------------

__global__ __launch_bounds__(256) void k_cast(const float* __restrict__ x, ushort* __restrict__ xb, int n4){
  int i = blockIdx.x*256 + threadIdx.x;
  if (i < n4){
    float4 v = ((const float4*)x)[i];
    uint2 p;
    p.x = (uint)f2bf(v.x) | ((uint)f2bf(v.y)<<16);
    p.y = (uint)f2bf(v.z) | ((uint)f2bf(v.w)<<16);
    ((uint2*)xb)[i] = p;
  }
}

// ---------------- weight -> B-fragment pack ----------------
// Bf[(nt*4+ks)*64 + lane] = 8 bf16: B[ks*32 + (lane>>4)*8 + j][nt*16 + (lane&15)]
// cols [0,n1) from B1 (stride n1), cols [n1, n1+n2) from B2 (stride n2).

__global__ __launch_bounds__(256) void k_bfrag(const float* __restrict__ B1, const float* __restrict__ B2,
                                               int n1, int n2, int NT, ushort* __restrict__ out){
  int i = blockIdx.x*256 + threadIdx.x;
  if (i >= NT*4*64) return;
  int l = i & 63, ks = (i>>6)&3, nt = i>>8;
  int col = nt*16 + (l&15);
  int k0  = ks*32 + (l>>4)*8;
  const float* B; int stride, c;
  if (col < n1){ B = B1; stride = n1; c = col; }
  else         { B = B2; stride = n2; c = col - n1; }
  ushort v[8];
  #pragma unroll
  for (int j=0;j<8;j++) v[j] = f2bf(B[(size_t)(k0+j)*stride + c]);
  uint4 pk;
  pk.x = (uint)v[0] | ((uint)v[1]<<16);
  pk.y = (uint)v[2] | ((uint)v[3]<<16);
  pk.z = (uint)v[4] | ((uint)v[5]<<16);
  pk.w = (uint)v[6] | ((uint)v[7]<<16);
  *(uint4*)(out + (size_t)i*8) = pk;
}

// ---------------- MFMA GEMM, K=128, no LDS ----------------
// A bf16 [M,128]; Bf pre-packed frags; cols [0,NTF*16) -> featb bf16 + el/er;
// cols [NTF*16, NT*16) -> Cres fp32. H = NTF/2 heads.

template<int NT, int NTF, int H>
__global__ __launch_bounds__(256) void k_gemm_mfma(const ushort* __restrict__ Ab, const ushort* __restrict__ Bf,
                                                   ushort* __restrict__ featb, float* __restrict__ Cres,
                                                   const float* __restrict__ al, const float* __restrict__ ar,
                                                   float* __restrict__ el, float* __restrict__ er, int M){
  int t = threadIdx.x;
  int l = t & 63, w = t >> 6;
  int rw = blockIdx.x*64 + w*16;
  int c = l & 15, g = l >> 4;

  f32x4 acc[NT];
  #pragma unroll
  for (int nt=0;nt<NT;nt++) acc[nt] = (f32x4){0.f,0.f,0.f,0.f};

  int rowA = rw + c; if (rowA >= M) rowA = M-1;
  const ushort* Ap = Ab + (size_t)rowA*128 + g*8;
  const bfrag* Bp = (const bfrag*)Bf;

  #pragma unroll
  for (int ks=0; ks<4; ++ks){
    bfrag a = *(const bfrag*)(Ap + ks*32);
    #pragma unroll
    for (int nt=0; nt<NT; ++nt){
      bfrag b = Bp[(nt*4+ks)*64 + l];
      acc[nt] = __builtin_amdgcn_mfma_f32_16x16x32_bf16(a, b, acc[nt], 0, 0, 0);
    }
  }

  float alv[H][2], arv[H][2];
  #pragma unroll
  for (int h=0;h<H;h++){
    alv[h][0]=al[h*32+c];    arv[h][0]=ar[h*32+c];
    alv[h][1]=al[h*32+16+c]; arv[h][1]=ar[h*32+16+c];
  }

  #pragma unroll
  for (int reg=0; reg<4; ++reg){
    int row = rw + g*4 + reg;
    bool ok = row < M;
    #pragma unroll
    for (int h=0;h<H;h++){
      float pl = acc[2*h][reg]*alv[h][0] + acc[2*h+1][reg]*alv[h][1];
      float pr = acc[2*h][reg]*arv[h][0] + acc[2*h+1][reg]*arv[h][1];
      #pragma unroll
      for (int off=1; off<16; off<<=1){ pl += __shfl_xor(pl,off); pr += __shfl_xor(pr,off); }
      if (ok && c==0){ el[(size_t)row*H + h] = pl; er[(size_t)row*H + h] = pr; }
    }
    if (ok){
      #pragma unroll
      for (int nt=0; nt<NTF; ++nt)
        featb[(size_t)row*(NTF*16) + nt*16 + c] = f2bf(acc[nt][reg]);
      #pragma unroll
      for (int nt=NTF; nt<NT; ++nt)
        Cres[(size_t)row*((NT-NTF)*16) + (nt-NTF)*16 + c] = acc[nt][reg];
    }
  }
}

// ---------------- aggregation: one wave per dst node, bf16 feat ----------------
// RK: residual kind 0=none 1=bf16 2=fp32.  OBF: output bf16.

template<int H, int RK, bool OBF>
__global__ __launch_bounds__(256) void k_agg(const int* __restrict__ rowptr, const int* __restrict__ csr,
                                             const ushort* __restrict__ feat,
                                             const float* __restrict__ el, const float* __restrict__ er,
                                             const void* __restrict__ res, const float* __restrict__ bias,
                                             void* __restrict__ out, int act){
  int lane = threadIdx.x & 63;
  int node = blockIdx.x*4 + (threadIdx.x >> 6);

  int beg = rowptr[node], end = rowptr[node+1];
  int deg = end - beg;
  int tot = deg*H;

  const ushort* resb = (const ushort*)res;
  const float*  resf = (const float*)res;

  // ---- pass 1: max ----
  int hA = lane & (H-1);
  float erA = er[(size_t)node*H + hA];
  float m = -INFINITY;
  float e0 = 0.f;
  if (lane < tot){
    int s = csr[beg + ((H==4) ? (lane>>2) : lane)];
    float e = el[(size_t)s*H + hA] + erA;
    e0 = (e > 0.f) ? e : 0.2f*e;
    m = e0;
  }
  for (int idx = lane+64; idx < tot; idx += 64){
    int s = csr[beg + ((H==4) ? (idx>>2) : idx)];
    float e = el[(size_t)s*H + hA] + erA;
    e = (e > 0.f) ? e : 0.2f*e;
    m = fmaxf(m, e);
  }
  #pragma unroll
  for (int off=H; off<64; off<<=1) m = fmaxf(m, __shfl_xor(m, off));

  // ---- pass 2: sum ----
  float ss = 0.f;
  if (lane < tot) ss = __expf(e0 - m);
  for (int idx = lane+64; idx < tot; idx += 64){
    int s = csr[beg + ((H==4) ? (idx>>2) : idx)];
    float e = el[(size_t)s*H + hA] + erA;
    e = (e > 0.f) ? e : 0.2f*e;
    ss += __expf(e - m);
  }
  #pragma unroll
  for (int off=H; off<64; off<<=1) ss += __shfl_xor(ss, off);

  // ---- pass 3: gather-accumulate ----
  if (H == 4){
    int g = lane >> 4;
    float mg  = __shfl(m, g);
    float sg  = __shfl(ss, g);
    float erg = er[(size_t)node*4 + g];
    float inv = (deg > 0) ? 1.f/sg : 0.f;
    float a0 = 0.f, a1 = 0.f;

    int ei = 0;
    for (; ei+2 <= deg; ei += 2){
      int s0 = csr[beg+ei], s1 = csr[beg+ei+1];
      uint p0 = *(const uint*)(feat + (size_t)s0*128 + 2*lane);
      uint p1 = *(const uint*)(feat + (size_t)s1*128 + 2*lane);
      float eA = el[(size_t)s0*4 + g] + erg;
      float eB = el[(size_t)s1*4 + g] + erg;
      eA = (eA>0.f)?eA:0.2f*eA;  eB = (eB>0.f)?eB:0.2f*eB;
      float wA = __expf(eA - mg) * inv;
      float wB = __expf(eB - mg) * inv;
      a0 += wA*bflo(p0) + wB*bflo(p1);
      a1 += wA*bfhi(p0) + wB*bfhi(p1);
    }
    if (ei < deg){
      int s0 = csr[beg+ei];
      uint p0 = *(const uint*)(feat + (size_t)s0*128 + 2*lane);
      float eA = el[(size_t)s0*4 + g] + erg;
      eA = (eA>0.f)?eA:0.2f*eA;
      float wA = __expf(eA - mg) * inv;
      a0 += wA*bflo(p0);
      a1 += wA*bfhi(p0);
    }

    float o0 = a0, o1 = a1;
    if (RK == 1){
      uint rv = *(const uint*)(resb + (size_t)node*128 + 2*lane);
      o0 += bflo(rv); o1 += bfhi(rv);
    } else if (RK == 2){
      float2 rv = *(const float2*)(resf + (size_t)node*128 + 2*lane);
      o0 += rv.x; o1 += rv.y;
    }
    o0 += bias[2*lane]; o1 += bias[2*lane+1];
    if (act){
      o0 = (o0>0.f) ? o0 : __expf(o0)-1.f;
      o1 = (o1>0.f) ? o1 : __expf(o1)-1.f;
    }
    if (OBF){
      uint pk = (uint)f2bf(o0) | ((uint)f2bf(o1)<<16);
      *(uint*)((ushort*)out + (size_t)node*128 + 2*lane) = pk;
    } else {
      float2 ov; ov.x = o0; ov.y = o1;
      *(float2*)((float*)out + (size_t)node*128 + 2*lane) = ov;
    }
  } else {
    float m0 = __shfl(m, 0);
    float s0v = __shfl(ss, 0);
    float er0 = er[node];
    float inv = (deg > 0) ? 1.f/s0v : 0.f;
    int sub = lane >> 4;
    int fl  = lane & 15;
    float a0 = 0.f, a1 = 0.f;
    for (int ei = sub; ei < deg; ei += 4){
      int s = csr[beg+ei];
      uint pv = *(const uint*)(feat + (size_t)s*32 + 2*fl);
      float e = el[s] + er0;
      e = (e>0.f)?e:0.2f*e;
      float w = __expf(e - m0) * inv;
      a0 += w*bflo(pv);
      a1 += w*bfhi(pv);
    }
    a0 += __shfl_xor(a0,16); a0 += __shfl_xor(a0,32);
    a1 += __shfl_xor(a1,16); a1 += __shfl_xor(a1,32);
    if (lane < 16){
      float o0 = a0, o1 = a1;
      if (RK == 1){
        uint rv = *(const uint*)(resb + (size_t)node*32 + 2*fl);
        o0 += bflo(rv); o1 += bfhi(rv);
      } else if (RK == 2){
        float2 rv = *(const float2*)(resf + (size_t)node*32 + 2*fl);
        o0 += rv.x; o1 += rv.y;
      }
      o0 += bias[2*fl]; o1 += bias[2*fl+1];
      if (act){
        o0 = (o0>0.f) ? o0 : __expf(o0)-1.f;
        o1 = (o1>0.f) ? o1 : __expf(o1)-1.f;
      }
      if (OBF){
        uint pk = (uint)f2bf(o0) | ((uint)f2bf(o1)<<16);
        *(uint*)((ushort*)out + (size_t)node*32 + 2*fl) = pk;
      } else {
        float2 ov; ov.x = o0; ov.y = o1;
        *(float2*)((float*)out + (size_t)node*32 + 2*fl) = ov;
      }
    }
  }
}

// ---------------- final FC: out[N,40] = h[N,32] @ Wfc[32,40] + bfc ----------------

__global__ __launch_bounds__(256) void k_fc(const float* __restrict__ h, const float* __restrict__ W,
                                            const float* __restrict__ b, float* __restrict__ out){
  __shared__ float Ws[32*40];
  __shared__ float Hs[64][33];
  __shared__ float bs[40];
  int t = threadIdx.x;
  for (int i=t; i<1280; i+=256) Ws[i] = W[i];
  if (t < 40) bs[t] = b[t];
  int n0 = blockIdx.x*64;
  for (int idx=t; idx<512; idx+=256){
    int r = idx>>3, c4 = idx&7;
    float4 v;
    if (n0 + r < NN) v = *(const float4*)(h + (size_t)(n0+r)*32 + c4*4);
    else v = make_float4(0.f,0.f,0.f,0.f);
    Hs[r][c4*4+0]=v.x; Hs[r][c4*4+1]=v.y; Hs[r][c4*4+2]=v.z; Hs[r][c4*4+3]=v.w;
  }
  __syncthreads();
  int n = t>>2, cg = t&3;
  float acc[10];
  #pragma unroll
  for (int j=0;j<10;j++) acc[j] = 0.f;
  #pragma unroll
  for (int k=0;k<32;k++){
    float hv = Hs[n][k];
    #pragma unroll
    for (int j=0;j<10;j++) acc[j] += hv * Ws[k*40 + cg + 4*j];
  }
  int row = n0 + n;
  if (row < NN){
    #pragma unroll
    for (int j=0;j<10;j++) out[(size_t)row*40 + cg + 4*j] = acc[j] + bs[cg+4*j];
  }
}

// ---------------- launch ----------------

extern "C" void kernel_launch(void* const* d_in, const int* in_sizes, int n_in,
                              void* d_out, int out_size, void* d_ws, size_t ws_size,
                              hipStream_t stream){
  const float* x    = (const float*)d_in[0];
  const int*   src  = (const int*)  d_in[1];
  const int*   dst  = (const int*)  d_in[2];
  const float* W1   = (const float*)d_in[3];
  const float* al1  = (const float*)d_in[4];
  const float* ar1  = (const float*)d_in[5];
  const float* b1   = (const float*)d_in[6];
  const float* W2   = (const float*)d_in[7];
  const float* al2  = (const float*)d_in[8];
  const float* ar2  = (const float*)d_in[9];
  const float* b2   = (const float*)d_in[10];
  const float* W3   = (const float*)d_in[11];
  const float* al3  = (const float*)d_in[12];
  const float* ar3  = (const float*)d_in[13];
  const float* b3   = (const float*)d_in[14];
  const float* res3 = (const float*)d_in[15];
  const float* Wfc  = (const float*)d_in[16];
  const float* bfc  = (const float*)d_in[17];
  float* out = (float*)d_out;

  char* ws = (char*)d_ws;
  size_t o = 0;
  auto alloc = [&](size_t bytes)->char*{
    char* p = ws + o;
    o += (bytes + 255) & ~(size_t)255;
    return p;
  };
  int*    rowptr = (int*)   alloc((size_t)(NN+1)*4);
  int*    cnt    = (int*)   alloc((size_t)NN*4);
  int*    cnt2   = (int*)   alloc((size_t)NN*4);
  int*    bsum   = (int*)   alloc(512*4);
  int*    boff   = (int*)   alloc(512*4);
  int*    csr    = (int*)   alloc((size_t)NE*4);
  float*  el     = (float*) alloc((size_t)NN*4*4);
  float*  er     = (float*) alloc((size_t)NN*4*4);
  ushort* xb     = (ushort*)alloc((size_t)NN*128*2);
  ushort* featb  = (ushort*)alloc((size_t)NN*128*2);
  ushort* h1b    = (ushort*)alloc((size_t)NN*128*2);
  ushort* h2b    = (ushort*)alloc((size_t)NN*128*2);
  float*  res3p  = (float*) alloc((size_t)NN*32*4);
  float*  h3     = (float*) alloc((size_t)NN*32*4);
  ushort* Bf1    = (ushort*)alloc((size_t)8*4*64*8*2);
  ushort* Bf2    = (ushort*)alloc((size_t)8*4*64*8*2);
  ushort* Bf3    = (ushort*)alloc((size_t)4*4*64*8*2);
  (void)ws_size; (void)n_in; (void)in_sizes; (void)out_size;

  // CSR build (graph identical across layers)
  hipMemsetAsync(cnt,  0, (size_t)NN*4, stream);
  hipMemsetAsync(cnt2, 0, (size_t)NN*4, stream);
  k_count<<<(NE+255)/256, 256, 0, stream>>>(dst, cnt);
  int nb = (NN+255)/256;
  k_scan_local<<<nb, 256, 0, stream>>>(cnt, rowptr, bsum);
  k_scan_bsum<<<1, 512, 0, stream>>>(bsum, boff, nb);
  k_scan_add<<<(NN+1+255)/256, 256, 0, stream>>>(rowptr, boff);
  k_fill<<<(NE+255)/256, 256, 0, stream>>>(src, dst, rowptr, cnt2, csr);

  // pre-casts / weight packs
  k_cast<<<(NN*128/4+255)/256, 256, 0, stream>>>(x, xb, NN*128/4);
  k_bfrag<<<8, 256, 0, stream>>>(W1, nullptr, 128, 0, 8, Bf1);
  k_bfrag<<<8, 256, 0, stream>>>(W2, nullptr, 128, 0, 8, Bf2);
  k_bfrag<<<4, 256, 0, stream>>>(W3, res3, 32, 32, 4, Bf3);

  int gemm_blocks = (NN+63)/64;

  // ---- Layer 1: 128 -> 4x32, no residual, ELU ----
  k_gemm_mfma<8,8,4><<<gemm_blocks, 256, 0, stream>>>(xb, Bf1, featb, nullptr, al1, ar1, el, er, NN);
  k_agg<4,0,true><<<NN/4, 256, 0, stream>>>(rowptr, csr, featb, el, er, nullptr, b1, h1b, 1);

  // ---- Layer 2: 128 -> 4x32, identity residual, ELU ----
  k_gemm_mfma<8,8,4><<<gemm_blocks, 256, 0, stream>>>(h1b, Bf2, featb, nullptr, al2, ar2, el, er, NN);
  k_agg<4,1,true><<<NN/4, 256, 0, stream>>>(rowptr, csr, featb, el, er, h1b, b2, h2b, 1);

  // ---- Layer 3: fused feat3 + projected residual, 1 head, no act ----
  k_gemm_mfma<4,2,1><<<gemm_blocks, 256, 0, stream>>>(h2b, Bf3, featb, res3p, al3, ar3, el, er, NN);
  k_agg<1,2,false><<<NN/4, 256, 0, stream>>>(rowptr, csr, featb, el, er, res3p, b3, h3, 0);

  // ---- classifier ----
  k_fc<<<gemm_blocks, 256, 0, stream>>>(h3, Wfc, bfc, out);
}